// Round 14
// baseline (548.919 us; speedup 1.0000x reference)
//
#include <hip/hip_runtime.h>

#define G 250
#define GG 62500
#define NB 8
#define HFEAT 2000000
#define W1STRIDE 2000064

typedef float f4v __attribute__((ext_vector_type(4)));

// ---------------- rasterize ----------------
__global__ void k_raster(const float* __restrict__ lidar, float* __restrict__ img) {
    int idx = blockIdx.x * blockDim.x + threadIdx.x;
    if (idx >= NB * 360 * 1000) return;
    int k = idx % 1000;
    int ba = idx / 1000;
    int a = ba % 360;
    int b = ba / 360;
    float r = lidar[ba];
    if (!(r > 0.0f && r < 1.0f)) return;
    float tmr = __fsub_rn(2.0f, r);
    int n = (int)floorf(__fmul_rn(tmr, 500.0f)) + 1;
    if (k >= n) return;
    float denom = (float)(n - 1);
    const float delta = 6.2831855f / 359.0f;      // fp32, matches jnp.linspace step
    float angle = __fmul_rn((float)a, delta);
    float mag = __fadd_rn(r, __fdiv_rn(__fmul_rn((float)k, tmr), denom));
    float c = cosf(angle);
    float s = sinf(angle);
    float px = __fadd_rn(125.0f, __fmul_rn(__fmul_rn(mag, c), 100.0f));
    float py = __fadd_rn(125.0f, __fmul_rn(__fmul_rn(mag, s), 100.0f));
    int xg = (int)px;   // trunc toward zero
    int yg = (int)py;
    if (xg >= 0 && xg < G && yg >= 0 && yg < G)
        img[b * GG + yg * G + xg] = 1.0f;
}

// ---------------- conv1: 1 -> 16 (standalone; c1 stays L2/L3-resident) -------
__global__ void k_conv1(const float* __restrict__ img, const float* __restrict__ w,
                        const float* __restrict__ bias, float* __restrict__ c1) {
    __shared__ float sw[144];
    __shared__ float sb[16];
    int t = threadIdx.x;
    if (t < 144) sw[t] = w[t];
    if (t < 16) sb[t] = bias[t];
    __syncthreads();
    int p = blockIdx.x * 256 + t;
    if (p >= NB * GG) return;
    int b = p / GG;
    int yx = p - b * GG;
    int y = yx / G;
    int x = yx - y * G;
    float in[9];
#pragma unroll
    for (int dy = 0; dy < 3; ++dy)
#pragma unroll
        for (int dx = 0; dx < 3; ++dx) {
            int gy = y + dy - 1, gx = x + dx - 1;
            in[dy * 3 + dx] = (gy >= 0 && gy < G && gx >= 0 && gx < G)
                                  ? img[b * GG + gy * G + gx] : 0.0f;
        }
#pragma unroll
    for (int co = 0; co < 16; ++co) {
        float a = sb[co];
#pragma unroll
        for (int k = 0; k < 9; ++k) a = fmaf(in[k], sw[co * 9 + k], a);
        c1[(b * 16 + co) * GG + yx] = fmaxf(a, 0.0f);
    }
}

// ---------------- fused conv2(16->32) + fc1 ----------------------------------
// Block = one image row y (250 blocks), 512 thr = 8 waves = 8 o-groups.
// Loop 8 groups of 4 co: conv2 computes h[4co][8b][row] into dbuf LDS; then
// each wave streams W (nt float4, aligned via xoff) for its 8 o-rows and FMAs
// vs LDS h. W read exactly once; h never goes to HBM; conv VALU overlaps the
// W stream across waves. Epilogue = R8's butterfly + atomics.
__global__ __launch_bounds__(512) void k_c2fc1(const float* __restrict__ c1,
                                               const float* __restrict__ w2,
                                               const float* __restrict__ b2,
                                               const float* __restrict__ W1,
                                               float* __restrict__ accout) {
    __shared__ float s_h[2][4][8][256];   // [buf][co4][b][x+xoff] = 64 KB
    __shared__ float s_w2[4608];
    __shared__ float s_b2[32];
    int t = threadIdx.x;
    int g = t >> 6;                // wave = o-group, rows 8g..8g+7
    int l = t & 63;
    int y = blockIdx.x;            // 0..249
    int xoff = (y & 1) << 1;       // aligns W float4 reads to 16 B

    for (int i = t; i < 4608; i += 512) s_w2[i] = w2[i];
    if (t < 32) s_b2[t] = b2[t];
    {   // zero s_h once; conv only writes valid x, pads stay 0 forever
        float* f = &s_h[0][0][0][0];
        for (int i = t; i < 2 * 4 * 8 * 256; i += 512) f[i] = 0.0f;
    }
    __syncthreads();

    // conv work item: thread -> (b, 4-px x-group); 504 active threads
    int ib = t / 63;
    int xg = t - ib * 63;
    int x0 = xg * 4;
    bool cvalid = t < 504;

    float acc[64];
#pragma unroll
    for (int i = 0; i < 64; ++i) acc[i] = 0.0f;

    auto CONV = [&](int grp, int p) {
        if (!cvalid) return;
        float ha[4][4];
#pragma unroll
        for (int c4 = 0; c4 < 4; ++c4)
#pragma unroll
            for (int q = 0; q < 4; ++q) ha[c4][q] = s_b2[grp * 4 + c4];
        for (int ci = 0; ci < 16; ++ci) {
            float win[3][6];
#pragma unroll
            for (int dy = 0; dy < 3; ++dy) {
                int ry = y - 1 + dy;
                const float* crow = c1 + ((size_t)(ib * 16 + ci)) * GG + ry * G;
#pragma unroll
                for (int cc = 0; cc < 6; ++cc) {
                    int rx = x0 - 1 + cc;
                    win[dy][cc] = (ry >= 0 && ry < G && rx >= 0 && rx < G)
                                      ? crow[rx] : 0.0f;
                }
            }
#pragma unroll
            for (int c4 = 0; c4 < 4; ++c4) {
                const float* wp = &s_w2[(grp * 4 + c4) * 144 + ci * 9];
                float w0 = wp[0], w1 = wp[1], w2v = wp[2], w3 = wp[3], w4 = wp[4],
                      w5 = wp[5], w6 = wp[6], w7 = wp[7], w8 = wp[8];
#pragma unroll
                for (int q = 0; q < 4; ++q) {
                    float a = ha[c4][q];
                    a = fmaf(win[0][q],     w0,  a);
                    a = fmaf(win[0][q + 1], w1,  a);
                    a = fmaf(win[0][q + 2], w2v, a);
                    a = fmaf(win[1][q],     w3,  a);
                    a = fmaf(win[1][q + 1], w4,  a);
                    a = fmaf(win[1][q + 2], w5,  a);
                    a = fmaf(win[2][q],     w6,  a);
                    a = fmaf(win[2][q + 1], w7,  a);
                    a = fmaf(win[2][q + 2], w8,  a);
                    ha[c4][q] = a;
                }
            }
        }
#pragma unroll
        for (int c4 = 0; c4 < 4; ++c4)
#pragma unroll
            for (int q = 0; q < 4; ++q) {
                int x = x0 + q;
                if (x < G) s_h[p][c4][ib][x + xoff] = fmaxf(ha[c4][q], 0.0f);
            }
    };

    auto FC1 = [&](int grp, int p) {
#pragma unroll
        for (int c4 = 0; c4 < 4; ++c4) {
            int co = grp * 4 + c4;
            size_t kb = (size_t)co * GG + (size_t)y * G - xoff + 4 * l;  // 16B-aligned
            float4 hx[8];
#pragma unroll
            for (int b = 0; b < 8; ++b)
                hx[b] = *(const float4*)&s_h[p][c4][b][4 * l];
#pragma unroll
            for (int oi = 0; oi < 8; ++oi) {
                f4v wv = __builtin_nontemporal_load(
                    (const f4v*)(W1 + (size_t)(g * 8 + oi) * W1STRIDE + kb));
#pragma unroll
                for (int b = 0; b < 8; ++b) {
                    float a = acc[oi * 8 + b];
                    a = fmaf(wv[0], hx[b].x, a);
                    a = fmaf(wv[1], hx[b].y, a);
                    a = fmaf(wv[2], hx[b].z, a);
                    a = fmaf(wv[3], hx[b].w, a);
                    acc[oi * 8 + b] = a;
                }
            }
        }
    };

    CONV(0, 0);
    __syncthreads();
    for (int grp = 0; grp < 8; ++grp) {
        int p = grp & 1;
        if (grp < 7) CONV(grp + 1, p ^ 1);
        FC1(grp, p);
        __syncthreads();
    }

    // transposing butterfly: lane l ends with full sum of value brev6(l)
    int cnt = 64;
#pragma unroll
    for (int st = 0; st < 6; ++st) {
        int half = cnt >> 1;
        bool up = (l >> st) & 1;
#pragma unroll
        for (int i = 0; i < half; ++i) {
            float send = up ? acc[i] : acc[i + half];
            float keep = up ? acc[i + half] : acc[i];
            float recv = __shfl_xor(send, 1 << st, 64);
            acc[i] = keep + recv;
        }
        cnt = half;
    }
    unsigned vi = __brev((unsigned)l) >> 26;   // value index = oi*8 + b
    atomicAdd(&accout[g * 64 + vi], acc[0]);   // accout layout [o][b]
}

// ---------------- finalize: wind MLP + fc1 tail + fc2 + fc3 ----------------
__global__ __launch_bounds__(512) void k_final(const float* __restrict__ wind,
                        const float* __restrict__ ww1, const float* __restrict__ wb1,
                        const float* __restrict__ ww2, const float* __restrict__ wb2,
                        const float* __restrict__ ww3, const float* __restrict__ wb3,
                        const float* __restrict__ W1, const float* __restrict__ fb1,
                        const float* __restrict__ acc,
                        const float* __restrict__ w2, const float* __restrict__ b2,
                        const float* __restrict__ w3, const float* __restrict__ b3,
                        float* __restrict__ out) {
    __shared__ float s1[8][64], s2[8][64], f1[8][64], f2[8][32];
    int t = threadIdx.x;
    int b = t >> 6;
    int o = t & 63;
    {
        float v = wb1[o] + ww1[o * 2] * wind[b * 2] + ww1[o * 2 + 1] * wind[b * 2 + 1];
        s1[b][o] = fmaxf(v, 0.0f);
    }
    __syncthreads();
    {
        float v = wb2[o];
        for (int k = 0; k < 64; ++k) v = fmaf(s1[b][k], ww2[o * 64 + k], v);
        s2[b][o] = fmaxf(v, 0.0f);
    }
    __syncthreads();
    {
        float v = wb3[o];
        for (int k = 0; k < 64; ++k) v = fmaf(s2[b][k], ww3[o * 64 + k], v);
        s1[b][o] = fmaxf(v, 0.0f);   // reuse s1 = wind output
    }
    __syncthreads();
    {
        float v = fb1[o] + acc[o * 8 + b];
        const float* wrow = W1 + (size_t)o * W1STRIDE + HFEAT;
        for (int k = 0; k < 64; ++k) v = fmaf(s1[b][k], wrow[k], v);
        f1[b][o] = fmaxf(v, 0.0f);
    }
    __syncthreads();
    if (o < 32) {
        float v = b2[o];
        for (int k = 0; k < 64; ++k) v = fmaf(f1[b][k], w2[o * 64 + k], v);
        f2[b][o] = fmaxf(v, 0.0f);
    }
    __syncthreads();
    for (int i = t; i < 1600; i += 512) {
        int bb = i / 200;
        int oo = i - bb * 200;
        float v = b3[oo];
        for (int k = 0; k < 32; ++k) v = fmaf(f2[bb][k], w3[oo * 32 + k], v);
        out[bb * 200 + oo] = v;
    }
}

extern "C" void kernel_launch(void* const* d_in, const int* in_sizes, int n_in,
                              void* d_out, int out_size, void* d_ws, size_t ws_size,
                              hipStream_t stream) {
    const float* lidar = (const float*)d_in[0];
    const float* wind  = (const float*)d_in[1];
    const float* ww1 = (const float*)d_in[2];
    const float* wb1 = (const float*)d_in[3];
    const float* ww2 = (const float*)d_in[4];
    const float* wb2 = (const float*)d_in[5];
    const float* ww3 = (const float*)d_in[6];
    const float* wb3 = (const float*)d_in[7];
    const float* c1w = (const float*)d_in[8];
    const float* c1b = (const float*)d_in[9];
    const float* c2w = (const float*)d_in[10];
    const float* c2b = (const float*)d_in[11];
    const float* fw1 = (const float*)d_in[12];
    const float* fb1 = (const float*)d_in[13];
    const float* fw2 = (const float*)d_in[14];
    const float* fb2 = (const float*)d_in[15];
    const float* fw3 = (const float*)d_in[16];
    const float* fb3 = (const float*)d_in[17];
    float* out = (float*)d_out;

    // ws layout (floats): img 500,000 | c1 8,000,000 | acc 512
    float* ws  = (float*)d_ws;
    float* img = ws;
    float* c1  = ws + 500000;
    float* acc = ws + 8500000;

    hipMemsetAsync(img, 0, 500000 * sizeof(float), stream);
    hipMemsetAsync(acc, 0, 512 * sizeof(float), stream);

    k_raster<<<(NB * 360 * 1000 + 255) / 256, 256, 0, stream>>>(lidar, img);
    k_conv1<<<(NB * GG + 255) / 256, 256, 0, stream>>>(img, c1w, c1b, c1);
    k_c2fc1<<<G, 512, 0, stream>>>(c1, c2w, c2b, fw1, acc);
    k_final<<<1, 512, 0, stream>>>(wind, ww1, wb1, ww2, wb2, ww3, wb3,
                                   fw1, fb1, acc, fw2, fb2, fw3, fb3, out);
}

// Round 15
// 232.353 us; speedup vs baseline: 2.3624x; 2.3624x over previous
//
#include <hip/hip_runtime.h>

#define G 250
#define GG 62500
#define NB 8
#define HFEAT 2000000
#define W1STRIDE 2000064
#define NCH 7813          // ceil(2,000,000 / 256)
#define SPAN 8            // chunks per block-pair (contiguous)

typedef float f4v __attribute__((ext_vector_type(4)));

// ---------------- rasterize ----------------
__global__ void k_raster(const float* __restrict__ lidar, float* __restrict__ img) {
    int idx = blockIdx.x * blockDim.x + threadIdx.x;
    if (idx >= NB * 360 * 1000) return;
    int k = idx % 1000;
    int ba = idx / 1000;
    int a = ba % 360;
    int b = ba / 360;
    float r = lidar[ba];
    if (!(r > 0.0f && r < 1.0f)) return;
    float tmr = __fsub_rn(2.0f, r);
    int n = (int)floorf(__fmul_rn(tmr, 500.0f)) + 1;
    if (k >= n) return;
    float denom = (float)(n - 1);
    const float delta = 6.2831855f / 359.0f;      // fp32, matches jnp.linspace step
    float angle = __fmul_rn((float)a, delta);
    float mag = __fadd_rn(r, __fdiv_rn(__fmul_rn((float)k, tmr), denom));
    float c = cosf(angle);
    float s = sinf(angle);
    float px = __fadd_rn(125.0f, __fmul_rn(__fmul_rn(mag, c), 100.0f));
    float py = __fadd_rn(125.0f, __fmul_rn(__fmul_rn(mag, s), 100.0f));
    int xg = (int)px;   // trunc toward zero
    int yg = (int)py;
    if (xg >= 0 && xg < G && yg >= 0 && yg < G)
        img[b * GG + yg * G + xg] = 1.0f;
}

// ---------------- fused conv1(1->16)+conv2(16->32) (R8-exact) ----------------
__global__ __launch_bounds__(256) void k_conv12(const float* __restrict__ img,
                                                const float* __restrict__ w1,
                                                const float* __restrict__ b1,
                                                const float* __restrict__ w2,
                                                const float* __restrict__ b2,
                                                float* __restrict__ h) {
    __shared__ float s_img[20][37];
    __shared__ float s_c1[16][18][35];
    __shared__ float s_w2[4608];
    __shared__ float s_w1[144];
    __shared__ float s_b1[16];
    int t = threadIdx.x;
    int bx = blockIdx.x, by = blockIdx.y, b = blockIdx.z;
    for (int i = t; i < 4608; i += 256) s_w2[i] = w2[i];
    if (t < 144) s_w1[t] = w1[t];
    if (t < 16) s_b1[t] = b1[t];
    int x0 = bx * 32 - 1, y0 = by * 16 - 1;   // c1-tile origin
    for (int i = t; i < 20 * 36; i += 256) {
        int r = i / 36, c = i - r * 36;
        int gy = y0 - 1 + r, gx = x0 - 1 + c;
        float v = 0.0f;
        if (gy >= 0 && gy < G && gx >= 0 && gx < G) v = img[b * GG + gy * G + gx];
        s_img[r][c] = v;
    }
    __syncthreads();
    for (int i = t; i < 612; i += 256) {
        int yy = i / 34, xx = i - yy * 34;
        int gy = y0 + yy, gx = x0 + xx;
        bool inb = (gy >= 0 && gy < G && gx >= 0 && gx < G);
        float iv[9];
#pragma unroll
        for (int dy = 0; dy < 3; ++dy)
#pragma unroll
            for (int dx = 0; dx < 3; ++dx)
                iv[dy * 3 + dx] = s_img[yy + dy][xx + dx];
#pragma unroll
        for (int co = 0; co < 16; ++co) {
            float a = s_b1[co];
#pragma unroll
            for (int k = 0; k < 9; ++k) a = fmaf(iv[k], s_w1[co * 9 + k], a);
            s_c1[co][yy][xx] = inb ? fmaxf(a, 0.0f) : 0.0f;
        }
    }
    __syncthreads();
    int pg = t & 63;
    int cog = t >> 6;
    int ry = pg >> 2;
    int rx = (pg & 3) * 8;
    float acc[8][8];
#pragma unroll
    for (int i = 0; i < 8; ++i)
#pragma unroll
        for (int j = 0; j < 8; ++j) acc[i][j] = 0.0f;
    for (int ci = 0; ci < 16; ++ci) {
        float in[3][10];
#pragma unroll
        for (int dy = 0; dy < 3; ++dy)
#pragma unroll
            for (int xx = 0; xx < 10; ++xx)
                in[dy][xx] = s_c1[ci][ry + dy][rx + xx];
#pragma unroll
        for (int coi = 0; coi < 8; ++coi) {
            const float* wp = &s_w2[(cog * 8 + coi) * 144 + ci * 9];
            float w0 = wp[0], w1v = wp[1], w2v = wp[2], w3 = wp[3], w4 = wp[4],
                  w5 = wp[5], w6 = wp[6], w7 = wp[7], w8 = wp[8];
#pragma unroll
            for (int px = 0; px < 8; ++px) {
                float a = acc[coi][px];
                a = fmaf(in[0][px],     w0,  a);
                a = fmaf(in[0][px + 1], w1v, a);
                a = fmaf(in[0][px + 2], w2v, a);
                a = fmaf(in[1][px],     w3,  a);
                a = fmaf(in[1][px + 1], w4,  a);
                a = fmaf(in[1][px + 2], w5,  a);
                a = fmaf(in[2][px],     w6,  a);
                a = fmaf(in[2][px + 1], w7,  a);
                a = fmaf(in[2][px + 2], w8,  a);
                acc[coi][px] = a;
            }
        }
    }
    int y = by * 16 + ry;
    if (y < G) {
#pragma unroll
        for (int coi = 0; coi < 8; ++coi) {
            int co = cog * 8 + coi;
            float bv = b2[co];
#pragma unroll
            for (int px = 0; px < 8; ++px) {
                int x = bx * 32 + rx + px;
                if (x < G)
                    h[((size_t)(b * 32 + co)) * GG + y * G + x] =
                        fmaxf(acc[coi][px] + bv, 0.0f);
            }
        }
    }
}

// ---------------- fc1: R8 structure + XCD-pairing block swizzle --------------
// Work partition identical to R8: span s, half in {0,1} -> rows 32*half..+31.
// NEW: both halves of a span land on the SAME XCD (same bid&7, adjacent slots)
// so the shared h chunks hit XCD-local L2 instead of being fetched twice.
// 1954 blocks = 8 XCDs x 244 slots + 2 leftover; slots pair as (2m, 2m+1).
__global__ __launch_bounds__(256) void k_fc1(const float* __restrict__ h,
                                             const float* __restrict__ W1,
                                             float* __restrict__ accout) {
    int t = threadIdx.x;
    int w = t >> 6;
    int l = t & 63;
    int bid = blockIdx.x;
    int xcd = bid & 7;
    int slot = bid >> 3;
    int s, half;
    if (slot < 244) {                 // paired region: 8*122 = 976 spans
        s = xcd * 122 + (slot >> 1);
        half = slot & 1;
    } else {                          // leftover bids 1952,1953 -> span 976
        s = 976;
        half = xcd;                   // xcd = 0,1 for the two leftover blocks
    }
    int g = (half << 2) | w;          // 0..7 -> rows 8g..8g+7
    int cbeg = s * SPAN;
    if (cbeg >= NCH) return;
    int cend = min(cbeg + SPAN, NCH);

    const float* wrow[8];
#pragma unroll
    for (int oi = 0; oi < 8; ++oi)
        wrow[oi] = W1 + (size_t)(g * 8 + oi) * W1STRIDE;

    float acc[64];
#pragma unroll
    for (int i = 0; i < 64; ++i) acc[i] = 0.0f;

    for (int c = cbeg; c < cend; ++c) {
        int j = c * 256 + l * 4;
        if (j < HFEAT) {
            f4v wv[8];
            float4 hv[8];
#pragma unroll
            for (int oi = 0; oi < 8; ++oi)
                wv[oi] = __builtin_nontemporal_load((const f4v*)(wrow[oi] + j));
#pragma unroll
            for (int b = 0; b < 8; ++b)
                hv[b] = *(const float4*)(h + (size_t)b * HFEAT + j);
#pragma unroll
            for (int oi = 0; oi < 8; ++oi) {
#pragma unroll
                for (int b = 0; b < 8; ++b) {
                    float a = acc[oi * 8 + b];
                    a = fmaf(wv[oi][0], hv[b].x, a);
                    a = fmaf(wv[oi][1], hv[b].y, a);
                    a = fmaf(wv[oi][2], hv[b].z, a);
                    a = fmaf(wv[oi][3], hv[b].w, a);
                    acc[oi * 8 + b] = a;
                }
            }
        }
    }

    // transposing butterfly: lane l ends with full sum of value brev6(l)
    int cnt = 64;
#pragma unroll
    for (int st = 0; st < 6; ++st) {
        int half2 = cnt >> 1;
        bool up = (l >> st) & 1;
#pragma unroll
        for (int i = 0; i < half2; ++i) {
            float send = up ? acc[i] : acc[i + half2];
            float keep = up ? acc[i + half2] : acc[i];
            float recv = __shfl_xor(send, 1 << st, 64);
            acc[i] = keep + recv;
        }
        cnt = half2;
    }
    unsigned vi = __brev((unsigned)l) >> 26;   // value index = oi*8 + b
    atomicAdd(&accout[g * 64 + vi], acc[0]);   // accout layout [o][b]
}

// ---------------- finalize: wind MLP + fc1 tail + fc2 + fc3 (R8-exact) -------
__global__ void k_final(const float* __restrict__ wind,
                        const float* __restrict__ ww1, const float* __restrict__ wb1,
                        const float* __restrict__ ww2, const float* __restrict__ wb2,
                        const float* __restrict__ ww3, const float* __restrict__ wb3,
                        const float* __restrict__ W1, const float* __restrict__ fb1,
                        const float* __restrict__ acc,
                        const float* __restrict__ w2, const float* __restrict__ b2,
                        const float* __restrict__ w3, const float* __restrict__ b3,
                        float* __restrict__ out) {
    __shared__ float s1[8][64], s2[8][64], f1[8][64], f2[8][32];
    int t = threadIdx.x;
    if (t < 64) {
        for (int b = 0; b < 8; ++b) {
            float v = wb1[t] + ww1[t * 2] * wind[b * 2] + ww1[t * 2 + 1] * wind[b * 2 + 1];
            s1[b][t] = fmaxf(v, 0.0f);
        }
    }
    __syncthreads();
    if (t < 64) {
        for (int b = 0; b < 8; ++b) {
            float v = wb2[t];
            for (int k = 0; k < 64; ++k) v = fmaf(s1[b][k], ww2[t * 64 + k], v);
            s2[b][t] = fmaxf(v, 0.0f);
        }
    }
    __syncthreads();
    if (t < 64) {
        for (int b = 0; b < 8; ++b) {
            float v = wb3[t];
            for (int k = 0; k < 64; ++k) v = fmaf(s2[b][k], ww3[t * 64 + k], v);
            s1[b][t] = fmaxf(v, 0.0f);   // reuse s1 = wind output
        }
    }
    __syncthreads();
    if (t < 64) {
        for (int b = 0; b < 8; ++b) {
            float v = fb1[t] + acc[t * 8 + b];
            const float* wrow = W1 + (size_t)t * W1STRIDE + HFEAT;
            for (int k = 0; k < 64; ++k) v = fmaf(s1[b][k], wrow[k], v);
            f1[b][t] = fmaxf(v, 0.0f);
        }
    }
    __syncthreads();
    if (t < 32) {
        for (int b = 0; b < 8; ++b) {
            float v = b2[t];
            for (int k = 0; k < 64; ++k) v = fmaf(f1[b][k], w2[t * 64 + k], v);
            f2[b][t] = fmaxf(v, 0.0f);
        }
    }
    __syncthreads();
    if (t < 200) {
        for (int b = 0; b < 8; ++b) {
            float v = b3[t];
            for (int k = 0; k < 32; ++k) v = fmaf(f2[b][k], w3[t * 32 + k], v);
            out[b * 200 + t] = v;
        }
    }
}

extern "C" void kernel_launch(void* const* d_in, const int* in_sizes, int n_in,
                              void* d_out, int out_size, void* d_ws, size_t ws_size,
                              hipStream_t stream) {
    const float* lidar = (const float*)d_in[0];
    const float* wind  = (const float*)d_in[1];
    const float* ww1 = (const float*)d_in[2];
    const float* wb1 = (const float*)d_in[3];
    const float* ww2 = (const float*)d_in[4];
    const float* wb2 = (const float*)d_in[5];
    const float* ww3 = (const float*)d_in[6];
    const float* wb3 = (const float*)d_in[7];
    const float* c1w = (const float*)d_in[8];
    const float* c1b = (const float*)d_in[9];
    const float* c2w = (const float*)d_in[10];
    const float* c2b = (const float*)d_in[11];
    const float* fw1 = (const float*)d_in[12];
    const float* fb1 = (const float*)d_in[13];
    const float* fw2 = (const float*)d_in[14];
    const float* fb2 = (const float*)d_in[15];
    const float* fw3 = (const float*)d_in[16];
    const float* fb3 = (const float*)d_in[17];
    float* out = (float*)d_out;

    // ws layout (floats): img 500,000 | h 16,000,000 | acc 512
    float* ws  = (float*)d_ws;
    float* img = ws;
    float* h   = ws + 500000;
    float* acc = ws + 16500000;

    hipMemsetAsync(img, 0, 500000 * sizeof(float), stream);
    hipMemsetAsync(acc, 0, 512 * sizeof(float), stream);

    k_raster<<<(NB * 360 * 1000 + 255) / 256, 256, 0, stream>>>(lidar, img);
    dim3 g2(8, 16, NB);
    k_conv12<<<g2, 256, 0, stream>>>(img, c1w, c1b, c2w, c2b, h);
    int nblk = 2 * ((NCH + SPAN - 1) / SPAN);   // 1954
    k_fc1<<<nblk, 256, 0, stream>>>(h, fw1, acc);
    k_final<<<1, 256, 0, stream>>>(wind, ww1, wb1, ww2, wb2, ww3, wb3,
                                   fw1, fb1, acc, fw2, fb2, fw3, fb3, out);
}